// Round 6
// baseline (992.683 us; speedup 1.0000x reference)
//
#include <hip/hip_runtime.h>

// ---------------------------------------------------------------------------
// 2-layer GCN + link-prediction dot products.
// R6: CSR eliminated. Records stay bucket-binned (391 buckets x 256 nodes);
// aggregation is edge-parallel into per-bucket LDS accumulators (ds_add_f32),
// which deletes fill2/eidx/rowptr/counts. Layer-2 GEMM fused into the same
// block (u never leaves LDS). deg via one-pass LDS histogram. One edge_dot.
//
//   seed    : gtail[b] = b*CAPB
//   passA1  : 8192-edge chunks -> grouped dense appends into bucket regions
//   degB    : per-bucket LDS histogram -> dinv
//   gemm1   : hs = (x@W1) * dinv
//   aggB1   : LDS-accumulate hs[src]; gs = relu(dinv*(acc+hs)+b1)*dinv
//   aggB2G  : LDS-accumulate gs[src]; u = dinv*(acc+gs) in LDS; z2 = u@W2+b2
//   edge_dot: logits[e] = dot(z2[a], z2[b])   (pos+neg in one launch)
// ---------------------------------------------------------------------------

#define BKN   256     // nodes per bucket
#define CAPB  10240   // record slots per bucket (mean 8184, +22 sigma)
#define CHUNK 8192    // edges per passA1 block

__global__ void seed_kernel(int* __restrict__ gtail, int nb) {
    int t = threadIdx.x;
    if (t < nb) gtail[t] = t * CAPB;
}

// one block per CHUNK of edges: LDS-staged grouped append into bucket regions
__global__ void passA1_kernel(const int* __restrict__ src, const int* __restrict__ dst, int E,
                              int* __restrict__ gtail, unsigned* __restrict__ tmp, int nb) {
    __shared__ int cnt[512];
    __shared__ int base[512];
    int t = threadIdx.x;
    int c0 = blockIdx.x * CHUNK;
    cnt[t] = 0; cnt[t + 256] = 0;
    __syncthreads();
    unsigned rec[32];   // (src | dlow<<20), static-indexed -> stays in VGPRs
    unsigned brk[32];   // (bucket<<16 | rank)
    #pragma unroll
    for (int j = 0; j < 32; ++j) {
        int e = c0 + t + j * 256;
        if (e < E) {
            int s = src[e], d = dst[e];
            int b = d >> 8;
            int r = atomicAdd(&cnt[b], 1);
            rec[j] = (unsigned)s | ((unsigned)(d & (BKN - 1)) << 20);
            brk[j] = ((unsigned)b << 16) | (unsigned)r;
        }
    }
    __syncthreads();
    for (int b = t; b < nb; b += 256)
        if (cnt[b] > 0) base[b] = atomicAdd(&gtail[b], cnt[b]);
    __syncthreads();
    #pragma unroll
    for (int j = 0; j < 32; ++j) {
        int e = c0 + t + j * 256;
        if (e < E) {
            int b = (int)(brk[j] >> 16), r = (int)(brk[j] & 0xFFFFu);
            tmp[base[b] + r] = rec[j];
        }
    }
}

// one block per bucket: LDS degree histogram -> dinv
__global__ void degB_kernel(const int* __restrict__ gtail, const unsigned* __restrict__ tmp,
                            float* __restrict__ dinv, int n) {
    int b = blockIdx.x;
    int t = threadIdx.x;
    int beg = b * CAPB, end = gtail[b];
    __shared__ int h[BKN];
    h[t] = 0;
    __syncthreads();
    for (int i = beg + t; i < end; i += 256)
        atomicAdd(&h[tmp[i] >> 20], 1);
    __syncthreads();
    int v = (b << 8) + t;
    if (v < n) dinv[v] = rsqrtf((float)h[t] + 1.0f);   // +1: self loop
}

// hs[row][c] = (sum_k x[row][k] * W1[k][c]) * dinv[row],  c in [0,16)
__global__ void gemm1_kernel(const float* __restrict__ x, const float* __restrict__ W1,
                             const float* __restrict__ dinv, float* __restrict__ hs, int n) {
    __shared__ float4 sW[1024];                   // 256x16 floats
    const float4* W14 = (const float4*)W1;
    for (int i = threadIdx.x; i < 1024; i += 256) sW[i] = W14[i];
    __syncthreads();
    int row = blockIdx.x * 256 + threadIdx.x;
    if (row >= n) return;
    const float4* x4 = (const float4*)(x + (size_t)row * 256);
    float4 a0 = {0,0,0,0}, a1 = {0,0,0,0}, a2 = {0,0,0,0}, a3 = {0,0,0,0};
    for (int k4 = 0; k4 < 64; ++k4) {
        float4 xv = x4[k4];
        #pragma unroll
        for (int j = 0; j < 4; ++j) {
            float xk = (j == 0) ? xv.x : (j == 1) ? xv.y : (j == 2) ? xv.z : xv.w;
            int k = (k4 << 2) + j;
            float4 w0 = sW[k * 4 + 0];
            float4 w1 = sW[k * 4 + 1];
            float4 w2 = sW[k * 4 + 2];
            float4 w3 = sW[k * 4 + 3];
            a0.x += xk * w0.x; a0.y += xk * w0.y; a0.z += xk * w0.z; a0.w += xk * w0.w;
            a1.x += xk * w1.x; a1.y += xk * w1.y; a1.z += xk * w1.z; a1.w += xk * w1.w;
            a2.x += xk * w2.x; a2.y += xk * w2.y; a2.z += xk * w2.z; a2.w += xk * w2.w;
            a3.x += xk * w3.x; a3.y += xk * w3.y; a3.z += xk * w3.z; a3.w += xk * w3.w;
        }
    }
    float di = dinv[row];
    float4* o = (float4*)(hs + (size_t)row * 16);
    a0.x *= di; a0.y *= di; a0.z *= di; a0.w *= di;
    a1.x *= di; a1.y *= di; a1.z *= di; a1.w *= di;
    a2.x *= di; a2.y *= di; a2.z *= di; a2.w *= di;
    a3.x *= di; a3.y *= di; a3.z *= di; a3.w *= di;
    o[0] = a0; o[1] = a1; o[2] = a2; o[3] = a3;
}

__device__ __forceinline__ void acc16(float* a, float4 h0, float4 h1, float4 h2, float4 h3) {
    atomicAdd(a + 0,  h0.x); atomicAdd(a + 1,  h0.y); atomicAdd(a + 2,  h0.z); atomicAdd(a + 3,  h0.w);
    atomicAdd(a + 4,  h1.x); atomicAdd(a + 5,  h1.y); atomicAdd(a + 6,  h1.z); atomicAdd(a + 7,  h1.w);
    atomicAdd(a + 8,  h2.x); atomicAdd(a + 9,  h2.y); atomicAdd(a + 10, h2.z); atomicAdd(a + 11, h2.w);
    atomicAdd(a + 12, h3.x); atomicAdd(a + 13, h3.y); atomicAdd(a + 14, h3.z); atomicAdd(a + 15, h3.w);
}

// layer-1 aggregate, edge-parallel into LDS: gs = relu(dinv*(acc+hs)+b1)*dinv
__global__ void aggB1_kernel(const int* __restrict__ gtail, const unsigned* __restrict__ tmp,
                             const float4* __restrict__ hs4, const float* __restrict__ dinv,
                             const float* __restrict__ b1, float4* __restrict__ gs4, int n) {
    int b = blockIdx.x;
    int t = threadIdx.x;
    int beg = b * CAPB, end = gtail[b];
    __shared__ float acc[BKN * 16];               // 16 KB
    for (int i = t; i < BKN * 16; i += 512) acc[i] = 0.0f;
    __syncthreads();
    for (int i = beg + t; i < end; i += 512) {
        unsigned r = tmp[i];
        int s = (int)(r & 0xFFFFF), j = (int)(r >> 20);
        const float4* h = &hs4[(size_t)s * 4];
        float4 h0 = h[0], h1 = h[1], h2 = h[2], h3 = h[3];
        acc16(&acc[j * 16], h0, h1, h2, h3);
    }
    __syncthreads();
    const float4* b14 = (const float4*)b1;
    for (int task = t; task < BKN * 4; task += 512) {
        int j = task >> 2, q = task & 3;
        int v = (b << 8) + j;
        if (v >= n) continue;
        float di = dinv[v];
        float4 h = hs4[(size_t)v * 4 + q];
        float4 bb = b14[q];
        const float* a = &acc[j * 16 + q * 4];
        float4 z;
        z.x = fmaxf(di * (a[0] + h.x) + bb.x, 0.0f) * di;
        z.y = fmaxf(di * (a[1] + h.y) + bb.y, 0.0f) * di;
        z.z = fmaxf(di * (a[2] + h.z) + bb.z, 0.0f) * di;
        z.w = fmaxf(di * (a[3] + h.w) + bb.w, 0.0f) * di;
        gs4[(size_t)v * 4 + q] = z;
    }
}

// layer-2 aggregate + fused GEMM: u = dinv*(acc+gs) in LDS; z2 = u@W2 + b2
__global__ void aggB2G_kernel(const int* __restrict__ gtail, const unsigned* __restrict__ tmp,
                              const float4* __restrict__ gs4, const float* __restrict__ dinv,
                              const float* __restrict__ W2, const float* __restrict__ b2,
                              float* __restrict__ z2, int n) {
    int b = blockIdx.x;
    int t = threadIdx.x;
    int beg = b * CAPB, end = gtail[b];
    __shared__ float acc[BKN * 16];               // 16 KB; later holds u
    __shared__ float sW[16 * 64];                 // 4 KB
    __shared__ float sb[64];
    for (int i = t; i < BKN * 16; i += 512) acc[i] = 0.0f;
    for (int i = t; i < 16 * 64; i += 512) sW[i] = W2[i];
    if (t < 64) sb[t] = b2[t];
    __syncthreads();
    for (int i = beg + t; i < end; i += 512) {
        unsigned r = tmp[i];
        int s = (int)(r & 0xFFFFF), j = (int)(r >> 20);
        const float4* g = &gs4[(size_t)s * 4];
        float4 g0 = g[0], g1 = g[1], g2 = g[2], g3 = g[3];
        acc16(&acc[j * 16], g0, g1, g2, g3);
    }
    __syncthreads();
    // u (in place in acc)
    for (int task = t; task < BKN * 4; task += 512) {
        int j = task >> 2, q = task & 3;
        int v = (b << 8) + j;
        float* a = &acc[j * 16 + q * 4];
        if (v < n) {
            float di = dinv[v];
            float4 g = gs4[(size_t)v * 4 + q];
            a[0] = di * (a[0] + g.x);
            a[1] = di * (a[1] + g.y);
            a[2] = di * (a[2] + g.z);
            a[3] = di * (a[3] + g.w);
        } else {
            a[0] = a[1] = a[2] = a[3] = 0.0f;
        }
    }
    __syncthreads();
    // z2[v][:] = u[v][:] @ W2 + b2 ; thread -> (node j = t>>1, cols half*32..)
    {
        int j = t >> 1, o0 = (t & 1) * 32;
        int v = (b << 8) + j;
        if (v < n) {
            float u[16];
            #pragma unroll
            for (int c = 0; c < 16; ++c) u[c] = acc[j * 16 + c];
            float o[32];
            #pragma unroll
            for (int oo = 0; oo < 32; ++oo) o[oo] = sb[o0 + oo];
            #pragma unroll
            for (int c = 0; c < 16; ++c) {
                float uc = u[c];
                const float* wrow = &sW[c * 64 + o0];
                #pragma unroll
                for (int oo = 0; oo < 32; ++oo) o[oo] += uc * wrow[oo];
            }
            float4* zp = (float4*)(z2 + (size_t)v * 64 + o0);
            #pragma unroll
            for (int oo = 0; oo < 8; ++oo)
                zp[oo] = make_float4(o[oo * 4], o[oo * 4 + 1], o[oo * 4 + 2], o[oo * 4 + 3]);
        }
    }
}

// 16 lanes per edge; pos then neg edges in one grid.
__global__ void edge_dot_kernel(const int* __restrict__ pa, const int* __restrict__ pb,
                                const int* __restrict__ na, const int* __restrict__ nb_,
                                int ET, const float4* __restrict__ z24, float* __restrict__ out) {
    int t = blockIdx.x * blockDim.x + threadIdx.x;
    int e = t >> 4, l = t & 15;
    if (e >= 2 * ET) return;
    int a, b;
    if (e < ET) { a = pa[e]; b = pb[e]; }
    else        { a = na[e - ET]; b = nb_[e - ET]; }
    float4 va = z24[(size_t)a * 16 + l];
    float4 vb = z24[(size_t)b * 16 + l];
    float p = va.x * vb.x + va.y * vb.y + va.z * vb.z + va.w * vb.w;
    p += __shfl_xor(p, 1);
    p += __shfl_xor(p, 2);
    p += __shfl_xor(p, 4);
    p += __shfl_xor(p, 8);
    if (l == 0) out[e] = p;
}

extern "C" void kernel_launch(void* const* d_in, const int* in_sizes, int n_in,
                              void* d_out, int out_size, void* d_ws, size_t ws_size,
                              hipStream_t stream) {
    const float* x    = (const float*)d_in[0];
    const int*   tei  = (const int*)d_in[1];
    const int*   tpos = (const int*)d_in[2];
    const int*   tneg = (const int*)d_in[3];
    const float* W1   = (const float*)d_in[4];
    const float* b1   = (const float*)d_in[5];
    const float* W2   = (const float*)d_in[6];
    const float* b2   = (const float*)d_in[7];
    float* out = (float*)d_out;

    int n  = in_sizes[0] / 256;     // 100000 nodes
    int E  = in_sizes[1] / 2;       // 3.2M train edges
    int ET = in_sizes[2] / 2;       // 500K test edges each
    int nb = (n + BKN - 1) / BKN;   // 391 buckets

    // workspace layout (no aliasing: aggB2G reads tmp and writes z2 concurrently
    // across blocks)
    char* w = (char*)d_ws;
    int*   gtail  = (int*)w;        w += 512 * 4;
    float* dinv   = (float*)w;      w += (size_t)n * 4;
    float* hs     = (float*)w;      w += (size_t)16 * n * 4;
    float* gs     = (float*)w;      w += (size_t)16 * n * 4;
    float* z2     = (float*)w;      w += (size_t)64 * n * 4;
    unsigned* tmp = (unsigned*)w;   w += (size_t)nb * CAPB * 4;

    const int* src = tei;
    const int* dst = tei + E;

    seed_kernel<<<1, 512, 0, stream>>>(gtail, nb);
    passA1_kernel<<<(E + CHUNK - 1) / CHUNK, 256, 0, stream>>>(src, dst, E, gtail, tmp, nb);
    degB_kernel<<<nb, 256, 0, stream>>>(gtail, tmp, dinv, n);
    gemm1_kernel<<<(n + 255) / 256, 256, 0, stream>>>(x, W1, dinv, hs, n);
    aggB1_kernel<<<nb, 512, 0, stream>>>(gtail, tmp, (const float4*)hs, dinv, b1,
                                         (float4*)gs, n);
    aggB2G_kernel<<<nb, 512, 0, stream>>>(gtail, tmp, (const float4*)gs, dinv, W2, b2, z2, n);
    edge_dot_kernel<<<(32 * ET + 255) / 256, 256, 0, stream>>>(tpos, tpos + ET, tneg, tneg + ET,
                                                               ET, (const float4*)z2, out);
}

// Round 7
// 415.290 us; speedup vs baseline: 2.3903x; 2.3903x over previous
//
#include <hip/hip_runtime.h>

// ---------------------------------------------------------------------------
// 2-layer GCN + link-prediction dot products.
// R7: revert R6's LDS-atomic aggregation (350us, occupancy-starved, atomic-
// serialized) back to R5's node-parallel CSR gather, plus:
//   - agg1: 8 lanes/node, unroll-4 gather prefetch, shuffle-merge halves
//   - agg2 fused with gemm2 (u staged in LDS; no u round-trip)
//   - single edge_dot launch, 2 edges per 16-lane group (4 gathers in flight)
//
// hs = (x@W1) * dinv
// gs = relu(dinv*(gather(hs)+hs)+b1) * dinv
// z2 = (dinv*(gather(gs)+gs)) @ W2 + b2
// logits[e] = dot(z2[a], z2[b])
// ---------------------------------------------------------------------------

#define CAP   18432   // slots per 512-node bucket (mean 16384, +16 sigma)
#define CHUNK 4096    // edges per passA1 block

__global__ void seed_kernel(int* __restrict__ gtail, int nb1) {
    int t = blockIdx.x * blockDim.x + threadIdx.x;
    if (t < nb1) gtail[t] = t * CAP;
}

// one block per CHUNK of edges: LDS-staged grouped append into bucket regions
__global__ void passA1_kernel(const int* __restrict__ src, const int* __restrict__ dst, int E,
                              int* __restrict__ gtail, unsigned* __restrict__ tmp, int nb1) {
    __shared__ int cnt[256];
    __shared__ int base[256];
    int t = threadIdx.x;
    int c0 = blockIdx.x * CHUNK;
    if (t < nb1) cnt[t] = 0;
    __syncthreads();
    unsigned rec[16];   // (src | dlow<<20)
    unsigned brk[16];   // (bucket<<16 | rank)
    #pragma unroll
    for (int j = 0; j < 16; ++j) {
        int e = c0 + t + j * 256;
        if (e < E) {
            int s = src[e], d = dst[e];
            int b = d >> 9;
            int r = atomicAdd(&cnt[b], 1);
            rec[j] = (unsigned)s | ((unsigned)(d & 511) << 20);
            brk[j] = ((unsigned)b << 16) | (unsigned)r;
        }
    }
    __syncthreads();
    if (t < nb1) base[t] = atomicAdd(&gtail[t], cnt[t]);
    __syncthreads();
    #pragma unroll
    for (int j = 0; j < 16; ++j) {
        int e = c0 + t + j * 256;
        if (e < E) {
            int b = (int)(brk[j] >> 16), r = (int)(brk[j] & 0xFFFFu);
            tmp[base[b] + r] = rec[j];
        }
    }
}

// one block per coarse bucket: stream records twice; 512-entry LDS hist/scan/
// cursors -> eidx placement + rowptr/counts/dinv emission.
__global__ void fill2_kernel(const int* __restrict__ gtail, const unsigned* __restrict__ tmp,
                             int* __restrict__ eidx, int* __restrict__ rowptr,
                             int* __restrict__ counts, float* __restrict__ dinv, int n) {
    int b = blockIdx.x;
    int t = threadIdx.x;
    int beg = b * CAP;
    int cnt_total = gtail[b] - beg;
    __shared__ int h[512];
    __shared__ int cur[512];
    h[t] = 0; h[t + 256] = 0;
    __syncthreads();
    for (int i = t; i < cnt_total; i += 256) {
        unsigned r = tmp[beg + i];
        atomicAdd(&h[r >> 20], 1);
    }
    __syncthreads();
    if (t == 0) {
        int run = beg;
        for (int j = 0; j < 512; ++j) { int c = h[j]; cur[j] = run; run += c; }
    }
    __syncthreads();
    for (int j = t; j < 512; j += 256) {
        int v = (b << 9) + j;
        if (v < n) {
            rowptr[v] = cur[j];
            counts[v] = h[j];
            dinv[v]   = rsqrtf((float)h[j] + 1.0f);   // +1: self loop
        }
    }
    __syncthreads();   // rowptr reads of cur must finish before placement mutates it
    for (int i = t; i < cnt_total; i += 256) {
        unsigned r = tmp[beg + i];
        int p = atomicAdd(&cur[r >> 20], 1);
        eidx[p] = (int)(r & 0xFFFFF);
    }
}

// hs[row][c] = (sum_k x[row][k] * W1[k][c]) * dinv[row],  c in [0,16)
__global__ void gemm1_kernel(const float* __restrict__ x, const float* __restrict__ W1,
                             const float* __restrict__ dinv, float* __restrict__ hs, int n) {
    __shared__ float4 sW[1024];                   // 256x16 floats
    const float4* W14 = (const float4*)W1;
    for (int i = threadIdx.x; i < 1024; i += 256) sW[i] = W14[i];
    __syncthreads();
    int row = blockIdx.x * 256 + threadIdx.x;
    if (row >= n) return;
    const float4* x4 = (const float4*)(x + (size_t)row * 256);
    float4 a0 = {0,0,0,0}, a1 = {0,0,0,0}, a2 = {0,0,0,0}, a3 = {0,0,0,0};
    for (int k4 = 0; k4 < 64; ++k4) {
        float4 xv = x4[k4];
        #pragma unroll
        for (int j = 0; j < 4; ++j) {
            float xk = (j == 0) ? xv.x : (j == 1) ? xv.y : (j == 2) ? xv.z : xv.w;
            int k = (k4 << 2) + j;
            float4 w0 = sW[k * 4 + 0];
            float4 w1 = sW[k * 4 + 1];
            float4 w2 = sW[k * 4 + 2];
            float4 w3 = sW[k * 4 + 3];
            a0.x += xk * w0.x; a0.y += xk * w0.y; a0.z += xk * w0.z; a0.w += xk * w0.w;
            a1.x += xk * w1.x; a1.y += xk * w1.y; a1.z += xk * w1.z; a1.w += xk * w1.w;
            a2.x += xk * w2.x; a2.y += xk * w2.y; a2.z += xk * w2.z; a2.w += xk * w2.w;
            a3.x += xk * w3.x; a3.y += xk * w3.y; a3.z += xk * w3.z; a3.w += xk * w3.w;
        }
    }
    float di = dinv[row];
    float4* o = (float4*)(hs + (size_t)row * 16);
    a0.x *= di; a0.y *= di; a0.z *= di; a0.w *= di;
    a1.x *= di; a1.y *= di; a1.z *= di; a1.w *= di;
    a2.x *= di; a2.y *= di; a2.z *= di; a2.w *= di;
    a3.x *= di; a3.y *= di; a3.z *= di; a3.w *= di;
    o[0] = a0; o[1] = a1; o[2] = a2; o[3] = a3;
}

// layer-1 aggregate: 8 lanes/node (2 per feature-quad), unroll-4 gathers.
__global__ void agg1_kernel(const int* __restrict__ rowptr, const int* __restrict__ counts,
                            const int* __restrict__ eidx, const float4* __restrict__ hs4,
                            const float* __restrict__ dinv, const float* __restrict__ b1,
                            float4* __restrict__ gs4, int n) {
    int t = blockIdx.x * blockDim.x + threadIdx.x;
    int v = t >> 3;
    if (v >= n) return;
    int q = t & 3, hh = (t >> 2) & 1;
    int start = rowptr[v], cnt = counts[v];
    float4 s = {0, 0, 0, 0};
    int i = hh;
    for (; i + 6 < cnt; i += 8) {
        int s0 = eidx[start + i];
        int s1 = eidx[start + i + 2];
        int s2 = eidx[start + i + 4];
        int s3 = eidx[start + i + 6];
        float4 h0 = hs4[(size_t)s0 * 4 + q];
        float4 h1 = hs4[(size_t)s1 * 4 + q];
        float4 h2 = hs4[(size_t)s2 * 4 + q];
        float4 h3 = hs4[(size_t)s3 * 4 + q];
        s.x += h0.x + h1.x + h2.x + h3.x;
        s.y += h0.y + h1.y + h2.y + h3.y;
        s.z += h0.z + h1.z + h2.z + h3.z;
        s.w += h0.w + h1.w + h2.w + h3.w;
    }
    for (; i < cnt; i += 2) {
        float4 h0 = hs4[(size_t)eidx[start + i] * 4 + q];
        s.x += h0.x; s.y += h0.y; s.z += h0.z; s.w += h0.w;
    }
    // merge the two edge-halves (lanes differing in bit 2)
    s.x += __shfl_xor(s.x, 4);
    s.y += __shfl_xor(s.y, 4);
    s.z += __shfl_xor(s.z, 4);
    s.w += __shfl_xor(s.w, 4);
    if (hh == 0) {
        float di = dinv[v];
        float4 h = hs4[(size_t)v * 4 + q];
        float4 b = ((const float4*)b1)[q];
        float4 z;
        z.x = fmaxf(di * (s.x + h.x) + b.x, 0.0f) * di;
        z.y = fmaxf(di * (s.y + h.y) + b.y, 0.0f) * di;
        z.z = fmaxf(di * (s.z + h.z) + b.z, 0.0f) * di;
        z.w = fmaxf(di * (s.w + h.w) + b.w, 0.0f) * di;
        gs4[(size_t)v * 4 + q] = z;
    }
}

// layer-2 aggregate fused with gemm2: u staged in LDS, z2 = u@W2 + b2.
// 256 threads = 32 nodes x 8 lanes.
__global__ void agg2g_kernel(const int* __restrict__ rowptr, const int* __restrict__ counts,
                             const int* __restrict__ eidx, const float4* __restrict__ gs4,
                             const float* __restrict__ dinv, const float* __restrict__ W2,
                             const float* __restrict__ b2, float* __restrict__ z2, int n) {
    __shared__ float su[32 * 16];   // u for this block's 32 nodes
    __shared__ float sW[16 * 64];
    __shared__ float sb[64];
    int t = threadIdx.x;
    for (int i = t; i < 16 * 64; i += 256) sW[i] = W2[i];
    if (t < 64) sb[t] = b2[t];

    int v = blockIdx.x * 32 + (t >> 3);
    int j = t >> 3, q = t & 3, hh = (t >> 2) & 1;
    if (v < n) {
        int start = rowptr[v], cnt = counts[v];
        float4 s = {0, 0, 0, 0};
        int i = hh;
        for (; i + 6 < cnt; i += 8) {
            int s0 = eidx[start + i];
            int s1 = eidx[start + i + 2];
            int s2 = eidx[start + i + 4];
            int s3 = eidx[start + i + 6];
            float4 g0 = gs4[(size_t)s0 * 4 + q];
            float4 g1 = gs4[(size_t)s1 * 4 + q];
            float4 g2 = gs4[(size_t)s2 * 4 + q];
            float4 g3 = gs4[(size_t)s3 * 4 + q];
            s.x += g0.x + g1.x + g2.x + g3.x;
            s.y += g0.y + g1.y + g2.y + g3.y;
            s.z += g0.z + g1.z + g2.z + g3.z;
            s.w += g0.w + g1.w + g2.w + g3.w;
        }
        for (; i < cnt; i += 2) {
            float4 g0 = gs4[(size_t)eidx[start + i] * 4 + q];
            s.x += g0.x; s.y += g0.y; s.z += g0.z; s.w += g0.w;
        }
        s.x += __shfl_xor(s.x, 4);
        s.y += __shfl_xor(s.y, 4);
        s.z += __shfl_xor(s.z, 4);
        s.w += __shfl_xor(s.w, 4);
        if (hh == 0) {
            float di = dinv[v];
            float4 g = gs4[(size_t)v * 4 + q];
            float* up = &su[j * 16 + q * 4];
            up[0] = di * (s.x + g.x);
            up[1] = di * (s.y + g.y);
            up[2] = di * (s.z + g.z);
            up[3] = di * (s.w + g.w);
        }
    }
    __syncthreads();
    // z2[v][o0..o0+8) : thread -> (node j = t>>3, 8 cols at o0=(t&7)*8)
    if (v < n) {
        int o0 = (t & 7) * 8;
        float u[16];
        #pragma unroll
        for (int c = 0; c < 16; ++c) u[c] = su[j * 16 + c];
        float o[8];
        #pragma unroll
        for (int oo = 0; oo < 8; ++oo) o[oo] = sb[o0 + oo];
        #pragma unroll
        for (int c = 0; c < 16; ++c) {
            float uc = u[c];
            const float* wrow = &sW[c * 64 + o0];
            #pragma unroll
            for (int oo = 0; oo < 8; ++oo) o[oo] += uc * wrow[oo];
        }
        float4* zp = (float4*)(z2 + (size_t)v * 64 + o0);
        zp[0] = make_float4(o[0], o[1], o[2], o[3]);
        zp[1] = make_float4(o[4], o[5], o[6], o[7]);
    }
}

// 16 lanes per pair: one pos edge + one neg edge (4 gathers in flight).
__global__ void edge_dot_kernel(const int* __restrict__ pa, const int* __restrict__ pb,
                                const int* __restrict__ na, const int* __restrict__ nb_,
                                int ET, const float4* __restrict__ z24, float* __restrict__ out) {
    int t = blockIdx.x * blockDim.x + threadIdx.x;
    int p = t >> 4, l = t & 15;
    if (p >= ET) return;
    int a0 = pa[p], b0 = pb[p];
    int a1 = na[p], b1 = nb_[p];
    float4 va0 = z24[(size_t)a0 * 16 + l];
    float4 vb0 = z24[(size_t)b0 * 16 + l];
    float4 va1 = z24[(size_t)a1 * 16 + l];
    float4 vb1 = z24[(size_t)b1 * 16 + l];
    float p0 = va0.x * vb0.x + va0.y * vb0.y + va0.z * vb0.z + va0.w * vb0.w;
    float p1 = va1.x * vb1.x + va1.y * vb1.y + va1.z * vb1.z + va1.w * vb1.w;
    p0 += __shfl_xor(p0, 1);  p1 += __shfl_xor(p1, 1);
    p0 += __shfl_xor(p0, 2);  p1 += __shfl_xor(p1, 2);
    p0 += __shfl_xor(p0, 4);  p1 += __shfl_xor(p1, 4);
    p0 += __shfl_xor(p0, 8);  p1 += __shfl_xor(p1, 8);
    if (l == 0) { out[p] = p0; out[ET + p] = p1; }
}

extern "C" void kernel_launch(void* const* d_in, const int* in_sizes, int n_in,
                              void* d_out, int out_size, void* d_ws, size_t ws_size,
                              hipStream_t stream) {
    const float* x    = (const float*)d_in[0];
    const int*   tei  = (const int*)d_in[1];
    const int*   tpos = (const int*)d_in[2];
    const int*   tneg = (const int*)d_in[3];
    const float* W1   = (const float*)d_in[4];
    const float* b1   = (const float*)d_in[5];
    const float* W2   = (const float*)d_in[6];
    const float* b2   = (const float*)d_in[7];
    float* out = (float*)d_out;

    int n   = in_sizes[0] / 256;    // 100000 nodes
    int E   = in_sizes[1] / 2;      // 3.2M train edges
    int ET  = in_sizes[2] / 2;      // 500K test edges each
    int nb1 = (n + 511) >> 9;       // 196 coarse buckets

    // workspace layout
    char* w = (char*)d_ws;
    int*   gtail  = (int*)w;        w += 256 * 4;
    int*   rowptr = (int*)w;        w += (size_t)n * 4;
    int*   counts = (int*)w;        w += (size_t)n * 4;
    float* dinv   = (float*)w;      w += (size_t)n * 4;
    float* hs     = (float*)w;      w += (size_t)16 * n * 4;
    float* gs     = (float*)w;      w += (size_t)16 * n * 4;
    float* z2     = (float*)w;      w += (size_t)64 * n * 4;
    int*   eidx   = (int*)w;        w += (size_t)nb1 * CAP * 4;
    unsigned* tmp = (unsigned*)z2;  // aliases z2: tmp dead before z2 written

    const int* src = tei;
    const int* dst = tei + E;

    seed_kernel<<<1, 256, 0, stream>>>(gtail, nb1);
    passA1_kernel<<<(E + CHUNK - 1) / CHUNK, 256, 0, stream>>>(src, dst, E, gtail, tmp, nb1);
    fill2_kernel<<<nb1, 256, 0, stream>>>(gtail, tmp, eidx, rowptr, counts, dinv, n);

    gemm1_kernel<<<(n + 255) / 256, 256, 0, stream>>>(x, W1, dinv, hs, n);
    agg1_kernel<<<(8 * n + 255) / 256, 256, 0, stream>>>(rowptr, counts, eidx,
                                                         (const float4*)hs, dinv, b1,
                                                         (float4*)gs, n);
    agg2g_kernel<<<(n + 31) / 32, 256, 0, stream>>>(rowptr, counts, eidx,
                                                    (const float4*)gs, dinv, W2, b2, z2, n);
    edge_dot_kernel<<<(16 * ET + 255) / 256, 256, 0, stream>>>(tpos, tpos + ET, tneg, tneg + ET,
                                                               ET, (const float4*)z2, out);
}

// Round 8
// 390.047 us; speedup vs baseline: 2.5450x; 1.0647x over previous
//
#include <hip/hip_runtime.h>

// ---------------------------------------------------------------------------
// 2-layer GCN + link-prediction dot products.
// R8 = R7 + edge-dot factorization:
//   z2[a].z2[b] = u[a] M u[b]^T + w2b.u[a] + w2b.u[b] + b2.b2,
//   M = W2 W2^T (16x16), w2b = W2 b2.  Per-node y[v] = u[v]M + w2b (16f),
//   c[v] = u[v].w2b (1f)  ->  logit = y[a].u[b] + c[a] + bb.
//   Edge gather: 2x64B+4B instead of 2x256B (R7 edge_dot fetched 220 MB HBM,
//   62us — z2 25.6MB >> 4MB per-XCD L2). z2 never materialized.
//
// hs = (x@W1) * dinv
// gs = relu(dinv*(gather(hs)+hs)+b1) * dinv
// u  = dinv*(gather(gs)+gs);  y = u@M + w2b;  c = u.w2b
// logits[e] = y[a].u[b] + c[a] + bb
// ---------------------------------------------------------------------------

#define CAP   18432   // slots per 512-node bucket (mean 16384, +16 sigma)
#define CHUNK 4096    // edges per passA1 block

__global__ void seed_kernel(int* __restrict__ gtail, int nb1) {
    int t = blockIdx.x * blockDim.x + threadIdx.x;
    if (t < nb1) gtail[t] = t * CAP;
}

// M = W2 W2^T, w2b = W2 b2, bb = b2.b2  ->  mw[0..255]=M, [256..271]=w2b, [272]=bb
__global__ void prep_kernel(const float* __restrict__ W2, const float* __restrict__ b2,
                            float* __restrict__ mw) {
    int t = threadIdx.x;
    int r = t >> 4, cc = t & 15;
    float s = 0.0f;
    for (int j = 0; j < 64; ++j) s += W2[r * 64 + j] * W2[cc * 64 + j];
    mw[t] = s;
    if (t < 16) {
        float w = 0.0f;
        for (int j = 0; j < 64; ++j) w += W2[t * 64 + j] * b2[j];
        mw[256 + t] = w;
    }
    if (t == 0) {
        float bbv = 0.0f;
        for (int j = 0; j < 64; ++j) bbv += b2[j] * b2[j];
        mw[272] = bbv;
    }
}

// one block per CHUNK of edges: LDS-staged grouped append into bucket regions
__global__ void passA1_kernel(const int* __restrict__ src, const int* __restrict__ dst, int E,
                              int* __restrict__ gtail, unsigned* __restrict__ tmp, int nb1) {
    __shared__ int cnt[256];
    __shared__ int base[256];
    int t = threadIdx.x;
    int c0 = blockIdx.x * CHUNK;
    if (t < nb1) cnt[t] = 0;
    __syncthreads();
    unsigned rec[16];   // (src | dlow<<20)
    unsigned brk[16];   // (bucket<<16 | rank)
    #pragma unroll
    for (int j = 0; j < 16; ++j) {
        int e = c0 + t + j * 256;
        if (e < E) {
            int s = src[e], d = dst[e];
            int b = d >> 9;
            int r = atomicAdd(&cnt[b], 1);
            rec[j] = (unsigned)s | ((unsigned)(d & 511) << 20);
            brk[j] = ((unsigned)b << 16) | (unsigned)r;
        }
    }
    __syncthreads();
    if (t < nb1) base[t] = atomicAdd(&gtail[t], cnt[t]);
    __syncthreads();
    #pragma unroll
    for (int j = 0; j < 16; ++j) {
        int e = c0 + t + j * 256;
        if (e < E) {
            int b = (int)(brk[j] >> 16), r = (int)(brk[j] & 0xFFFFu);
            tmp[base[b] + r] = rec[j];
        }
    }
}

// one block per coarse bucket: stream records twice; 512-entry LDS hist/scan/
// cursors -> eidx placement + rowptr/counts/dinv emission.
__global__ void fill2_kernel(const int* __restrict__ gtail, const unsigned* __restrict__ tmp,
                             int* __restrict__ eidx, int* __restrict__ rowptr,
                             int* __restrict__ counts, float* __restrict__ dinv, int n) {
    int b = blockIdx.x;
    int t = threadIdx.x;
    int beg = b * CAP;
    int cnt_total = gtail[b] - beg;
    __shared__ int h[512];
    __shared__ int cur[512];
    h[t] = 0; h[t + 256] = 0;
    __syncthreads();
    for (int i = t; i < cnt_total; i += 256) {
        unsigned r = tmp[beg + i];
        atomicAdd(&h[r >> 20], 1);
    }
    __syncthreads();
    if (t == 0) {
        int run = beg;
        for (int j = 0; j < 512; ++j) { int c = h[j]; cur[j] = run; run += c; }
    }
    __syncthreads();
    for (int j = t; j < 512; j += 256) {
        int v = (b << 9) + j;
        if (v < n) {
            rowptr[v] = cur[j];
            counts[v] = h[j];
            dinv[v]   = rsqrtf((float)h[j] + 1.0f);   // +1: self loop
        }
    }
    __syncthreads();   // rowptr reads of cur must finish before placement mutates it
    for (int i = t; i < cnt_total; i += 256) {
        unsigned r = tmp[beg + i];
        int p = atomicAdd(&cur[r >> 20], 1);
        eidx[p] = (int)(r & 0xFFFFF);
    }
}

// hs[row][c] = (sum_k x[row][k] * W1[k][c]) * dinv[row],  c in [0,16)
__global__ void gemm1_kernel(const float* __restrict__ x, const float* __restrict__ W1,
                             const float* __restrict__ dinv, float* __restrict__ hs, int n) {
    __shared__ float4 sW[1024];                   // 256x16 floats
    const float4* W14 = (const float4*)W1;
    for (int i = threadIdx.x; i < 1024; i += 256) sW[i] = W14[i];
    __syncthreads();
    int row = blockIdx.x * 256 + threadIdx.x;
    if (row >= n) return;
    const float4* x4 = (const float4*)(x + (size_t)row * 256);
    float4 a0 = {0,0,0,0}, a1 = {0,0,0,0}, a2 = {0,0,0,0}, a3 = {0,0,0,0};
    for (int k4 = 0; k4 < 64; ++k4) {
        float4 xv = x4[k4];
        #pragma unroll
        for (int j = 0; j < 4; ++j) {
            float xk = (j == 0) ? xv.x : (j == 1) ? xv.y : (j == 2) ? xv.z : xv.w;
            int k = (k4 << 2) + j;
            float4 w0 = sW[k * 4 + 0];
            float4 w1 = sW[k * 4 + 1];
            float4 w2 = sW[k * 4 + 2];
            float4 w3 = sW[k * 4 + 3];
            a0.x += xk * w0.x; a0.y += xk * w0.y; a0.z += xk * w0.z; a0.w += xk * w0.w;
            a1.x += xk * w1.x; a1.y += xk * w1.y; a1.z += xk * w1.z; a1.w += xk * w1.w;
            a2.x += xk * w2.x; a2.y += xk * w2.y; a2.z += xk * w2.z; a2.w += xk * w2.w;
            a3.x += xk * w3.x; a3.y += xk * w3.y; a3.z += xk * w3.z; a3.w += xk * w3.w;
        }
    }
    float di = dinv[row];
    float4* o = (float4*)(hs + (size_t)row * 16);
    a0.x *= di; a0.y *= di; a0.z *= di; a0.w *= di;
    a1.x *= di; a1.y *= di; a1.z *= di; a1.w *= di;
    a2.x *= di; a2.y *= di; a2.z *= di; a2.w *= di;
    a3.x *= di; a3.y *= di; a3.z *= di; a3.w *= di;
    o[0] = a0; o[1] = a1; o[2] = a2; o[3] = a3;
}

// layer-1 aggregate: 8 lanes/node (2 per feature-quad), unroll-4 gathers.
__global__ void agg1_kernel(const int* __restrict__ rowptr, const int* __restrict__ counts,
                            const int* __restrict__ eidx, const float4* __restrict__ hs4,
                            const float* __restrict__ dinv, const float* __restrict__ b1,
                            float4* __restrict__ gs4, int n) {
    int t = blockIdx.x * blockDim.x + threadIdx.x;
    int v = t >> 3;
    if (v >= n) return;
    int q = t & 3, hh = (t >> 2) & 1;
    int start = rowptr[v], cnt = counts[v];
    float4 s = {0, 0, 0, 0};
    int i = hh;
    for (; i + 6 < cnt; i += 8) {
        int s0 = eidx[start + i];
        int s1 = eidx[start + i + 2];
        int s2 = eidx[start + i + 4];
        int s3 = eidx[start + i + 6];
        float4 h0 = hs4[(size_t)s0 * 4 + q];
        float4 h1 = hs4[(size_t)s1 * 4 + q];
        float4 h2 = hs4[(size_t)s2 * 4 + q];
        float4 h3 = hs4[(size_t)s3 * 4 + q];
        s.x += h0.x + h1.x + h2.x + h3.x;
        s.y += h0.y + h1.y + h2.y + h3.y;
        s.z += h0.z + h1.z + h2.z + h3.z;
        s.w += h0.w + h1.w + h2.w + h3.w;
    }
    for (; i < cnt; i += 2) {
        float4 h0 = hs4[(size_t)eidx[start + i] * 4 + q];
        s.x += h0.x; s.y += h0.y; s.z += h0.z; s.w += h0.w;
    }
    // merge the two edge-halves (lanes differing in bit 2)
    s.x += __shfl_xor(s.x, 4);
    s.y += __shfl_xor(s.y, 4);
    s.z += __shfl_xor(s.z, 4);
    s.w += __shfl_xor(s.w, 4);
    if (hh == 0) {
        float di = dinv[v];
        float4 h = hs4[(size_t)v * 4 + q];
        float4 b = ((const float4*)b1)[q];
        float4 z;
        z.x = fmaxf(di * (s.x + h.x) + b.x, 0.0f) * di;
        z.y = fmaxf(di * (s.y + h.y) + b.y, 0.0f) * di;
        z.z = fmaxf(di * (s.z + h.z) + b.z, 0.0f) * di;
        z.w = fmaxf(di * (s.w + h.w) + b.w, 0.0f) * di;
        gs4[(size_t)v * 4 + q] = z;
    }
}

// layer-2 aggregate + factorized epilogue: u = dinv*(gather(gs)+gs);
// y = u@M + w2b; c = u.w2b.  256 threads = 32 nodes x 8 lanes.
__global__ void agg2y_kernel(const int* __restrict__ rowptr, const int* __restrict__ counts,
                             const int* __restrict__ eidx, const float4* __restrict__ gs4,
                             const float* __restrict__ dinv, const float* __restrict__ mw,
                             float4* __restrict__ u4, float* __restrict__ y,
                             float* __restrict__ c, int n) {
    __shared__ float su[32 * 16];   // u for this block's 32 nodes
    __shared__ float sM[256];
    __shared__ float sw[16];
    int t = threadIdx.x;
    sM[t] = mw[t];
    if (t < 16) sw[t] = mw[256 + t];

    int j = t >> 3, q = t & 3, hh = (t >> 2) & 1;
    int v = blockIdx.x * 32 + j;
    if (v < n) {
        int start = rowptr[v], cnt = counts[v];
        float4 s = {0, 0, 0, 0};
        int i = hh;
        for (; i + 6 < cnt; i += 8) {
            int s0 = eidx[start + i];
            int s1 = eidx[start + i + 2];
            int s2 = eidx[start + i + 4];
            int s3 = eidx[start + i + 6];
            float4 g0 = gs4[(size_t)s0 * 4 + q];
            float4 g1 = gs4[(size_t)s1 * 4 + q];
            float4 g2 = gs4[(size_t)s2 * 4 + q];
            float4 g3 = gs4[(size_t)s3 * 4 + q];
            s.x += g0.x + g1.x + g2.x + g3.x;
            s.y += g0.y + g1.y + g2.y + g3.y;
            s.z += g0.z + g1.z + g2.z + g3.z;
            s.w += g0.w + g1.w + g2.w + g3.w;
        }
        for (; i < cnt; i += 2) {
            float4 g0 = gs4[(size_t)eidx[start + i] * 4 + q];
            s.x += g0.x; s.y += g0.y; s.z += g0.z; s.w += g0.w;
        }
        s.x += __shfl_xor(s.x, 4);
        s.y += __shfl_xor(s.y, 4);
        s.z += __shfl_xor(s.z, 4);
        s.w += __shfl_xor(s.w, 4);
        if (hh == 0) {
            float di = dinv[v];
            float4 g = gs4[(size_t)v * 4 + q];
            float4 uu;
            uu.x = di * (s.x + g.x);
            uu.y = di * (s.y + g.y);
            uu.z = di * (s.z + g.z);
            uu.w = di * (s.w + g.w);
            float* up = &su[j * 16 + q * 4];
            up[0] = uu.x; up[1] = uu.y; up[2] = uu.z; up[3] = uu.w;
            u4[(size_t)v * 4 + q] = uu;
        }
    }
    __syncthreads();
    if (v < n) {
        int l8 = t & 7;
        const float* uu = &su[j * 16];
        int c0 = l8 * 2;
        float y0 = sw[c0], y1 = sw[c0 + 1];
        #pragma unroll
        for (int k = 0; k < 16; ++k) {
            float uk = uu[k];
            y0 += uk * sM[k * 16 + c0];
            y1 += uk * sM[k * 16 + c0 + 1];
        }
        float2* yp = (float2*)(y + (size_t)v * 16 + c0);
        *yp = make_float2(y0, y1);
        if (l8 == 0) {
            float cv = 0.0f;
            #pragma unroll
            for (int k = 0; k < 16; ++k) cv += uu[k] * sw[k];
            c[v] = cv;
        }
    }
}

// 16 lanes per pair: one pos edge + one neg edge.
// logit = y[a].u[b] + c[a] + bb
__global__ void edge_dot_kernel(const int* __restrict__ pa, const int* __restrict__ pb,
                                const int* __restrict__ na, const int* __restrict__ nb_,
                                int ET, const float* __restrict__ u, const float* __restrict__ y,
                                const float* __restrict__ c, const float* __restrict__ mw,
                                float* __restrict__ out) {
    int t = blockIdx.x * blockDim.x + threadIdx.x;
    int p = t >> 4, l = t & 15;
    if (p >= ET) return;
    int a0 = pa[p], b0 = pb[p];
    int a1 = na[p], b1 = nb_[p];
    float ya0 = y[(size_t)a0 * 16 + l];
    float ub0 = u[(size_t)b0 * 16 + l];
    float ya1 = y[(size_t)a1 * 16 + l];
    float ub1 = u[(size_t)b1 * 16 + l];
    float p0 = ya0 * ub0;
    float p1 = ya1 * ub1;
    p0 += __shfl_xor(p0, 1);  p1 += __shfl_xor(p1, 1);
    p0 += __shfl_xor(p0, 2);  p1 += __shfl_xor(p1, 2);
    p0 += __shfl_xor(p0, 4);  p1 += __shfl_xor(p1, 4);
    p0 += __shfl_xor(p0, 8);  p1 += __shfl_xor(p1, 8);
    if (l == 0) {
        float bb = mw[272];
        out[p]      = p0 + c[a0] + bb;
        out[ET + p] = p1 + c[a1] + bb;
    }
}

extern "C" void kernel_launch(void* const* d_in, const int* in_sizes, int n_in,
                              void* d_out, int out_size, void* d_ws, size_t ws_size,
                              hipStream_t stream) {
    const float* x    = (const float*)d_in[0];
    const int*   tei  = (const int*)d_in[1];
    const int*   tpos = (const int*)d_in[2];
    const int*   tneg = (const int*)d_in[3];
    const float* W1   = (const float*)d_in[4];
    const float* b1   = (const float*)d_in[5];
    const float* W2   = (const float*)d_in[6];
    const float* b2   = (const float*)d_in[7];
    float* out = (float*)d_out;

    int n   = in_sizes[0] / 256;    // 100000 nodes
    int E   = in_sizes[1] / 2;      // 3.2M train edges
    int ET  = in_sizes[2] / 2;      // 500K test edges each
    int nb1 = (n + 511) >> 9;       // 196 coarse buckets

    // workspace layout (no aliasing)
    char* w = (char*)d_ws;
    int*   gtail  = (int*)w;        w += 256 * 4;
    float* mw     = (float*)w;      w += 512 * 4;
    int*   rowptr = (int*)w;        w += (size_t)n * 4;
    int*   counts = (int*)w;        w += (size_t)n * 4;
    float* dinv   = (float*)w;      w += (size_t)n * 4;
    float* hs     = (float*)w;      w += (size_t)16 * n * 4;
    float* gs     = (float*)w;      w += (size_t)16 * n * 4;
    float* u      = (float*)w;      w += (size_t)16 * n * 4;
    float* y      = (float*)w;      w += (size_t)16 * n * 4;
    float* c      = (float*)w;      w += (size_t)n * 4;
    int*   eidx   = (int*)w;        w += (size_t)nb1 * CAP * 4;
    unsigned* tmp = (unsigned*)w;   w += (size_t)nb1 * CAP * 4;

    const int* src = tei;
    const int* dst = tei + E;

    seed_kernel<<<1, 256, 0, stream>>>(gtail, nb1);
    prep_kernel<<<1, 256, 0, stream>>>(W2, b2, mw);
    passA1_kernel<<<(E + CHUNK - 1) / CHUNK, 256, 0, stream>>>(src, dst, E, gtail, tmp, nb1);
    fill2_kernel<<<nb1, 256, 0, stream>>>(gtail, tmp, eidx, rowptr, counts, dinv, n);

    gemm1_kernel<<<(n + 255) / 256, 256, 0, stream>>>(x, W1, dinv, hs, n);
    agg1_kernel<<<(8 * n + 255) / 256, 256, 0, stream>>>(rowptr, counts, eidx,
                                                         (const float4*)hs, dinv, b1,
                                                         (float4*)gs, n);
    agg2y_kernel<<<(n + 31) / 32, 256, 0, stream>>>(rowptr, counts, eidx,
                                                    (const float4*)gs, dinv, mw,
                                                    (float4*)u, y, c, n);
    edge_dot_kernel<<<(16 * ET + 255) / 256, 256, 0, stream>>>(tpos, tpos + ET, tneg, tneg + ET,
                                                               ET, u, y, c, mw, out);
}